// Round 10
// baseline (335.395 us; speedup 1.0000x reference)
//
#include <hip/hip_runtime.h>
#include <float.h>

// Grid dims from the reference
#define BDIM 4
#define ZDIM 6
#define YDIM 200
#define XDIM 176
#define CDIM 64
#define KSLOTS (BDIM * ZDIM * YDIM * XDIM)  // 844800
#define BINV 64                              // voxels per bin
#define NBIN (KSLOTS / BINV)                 // 13200
#define NBIN2 (2 * NBIN)                     // 26400
#define SCAN_T 1024
#define EPT 26                               // 1024*26 = 26624 >= 26400
// tier-2 (fixed-cap, round-8) constants
#define CAP1 64
#define CAP2 192
#define CAPT (CAP1 + CAP2)
#define OVFCAP 16384
// staged-path LDS record caps (tail loop handles overflow exactly)
#define RCAP1 192
#define RCAP2 448

typedef float f32x4 __attribute__((ext_vector_type(4)));
typedef float f32x2 __attribute__((ext_vector_type(2)));

__device__ __forceinline__ int voxel_key4(const int4 c) {
    return ((c.x * ZDIM + c.y) * YDIM + c.z) * XDIM + c.w;
}
// monotonic float<->uint order encoding; 0u = "empty" sentinel (below all reals)
__device__ __forceinline__ unsigned ord_enc(float f) {
    unsigned u = __float_as_uint(f);
    return (u & 0x80000000u) ? ~u : (u | 0x80000000u);
}
__device__ __forceinline__ float ord_dec(unsigned u) {
    return (u & 0x80000000u) ? __uint_as_float(u & 0x7FFFFFFFu)
                             : __uint_as_float(~u);
}
__device__ __forceinline__ unsigned bf16rne(float x) {  // f32 -> bf16 bits (RNE)
    unsigned b = __float_as_uint(x);
    return (b + 0x7FFFu + ((b >> 16) & 1u)) >> 16;
}
__device__ __forceinline__ float bf16lo(unsigned u) { return __uint_as_float(u << 16); }
__device__ __forceinline__ float bf16hi(unsigned u) { return __uint_as_float(u & 0xFFFF0000u); }

// ================= TIER 1: exact-CSR + bf16 staging (sequential reads) ======

// Histogram both coord sets into cnt[NBIN2] (set2 at offset NBIN).
__global__ void hist2_kernel(const int* __restrict__ c1, int n1,
                             const int* __restrict__ c2, int n2,
                             int* __restrict__ cnt) {
    int i = blockIdx.x * blockDim.x + threadIdx.x;
    if (i < n1) {
        int4 cc = *reinterpret_cast<const int4*>(c1 + (long long)i * 4);
        atomicAdd(&cnt[voxel_key4(cc) >> 6], 1);
    } else if (i < n1 + n2) {
        int j = i - n1;
        int4 cc = *reinterpret_cast<const int4*>(c2 + (long long)j * 4);
        atomicAdd(&cnt[NBIN + (voxel_key4(cc) >> 6)], 1);
    }
}

// Single-block exclusive scan over cnt[NBIN2]; writes starts into pos[] AND
// resets cnt[] to the start (cnt becomes the scatter cursor -> ends).
__global__ __launch_bounds__(SCAN_T) void scan_kernel(int* __restrict__ cnt,
                                                      int* __restrict__ pos) {
    __shared__ int wsum[SCAN_T / 64];
    int t = threadIdx.x;
    int base = t * EPT;
    int v[EPT];
    int s = 0;
    #pragma unroll
    for (int i = 0; i < EPT; ++i) {
        v[i] = (base + i < NBIN2) ? cnt[base + i] : 0;
        s += v[i];
    }
    int lane = t & 63, wid = t >> 6;
    int x = s;
    #pragma unroll
    for (int off = 1; off < 64; off <<= 1) {
        int y = __shfl_up(x, off, 64);
        if (lane >= off) x += y;
    }
    if (lane == 63) wsum[wid] = x;
    __syncthreads();
    if (t < SCAN_T / 64) {
        int w = wsum[t];
        int xx = w;
        #pragma unroll
        for (int off = 1; off < SCAN_T / 64; off <<= 1) {
            int y = __shfl_up(xx, off, SCAN_T / 64);
            if (t >= off) xx += y;
        }
        wsum[t] = xx - w;
    }
    __syncthreads();
    int run = wsum[wid] + x - s;
    #pragma unroll
    for (int i = 0; i < EPT; ++i) {
        if (base + i < NBIN2) { pos[base + i] = run; cnt[base + i] = run; }
        run += v[i];
    }
}

// Scatter: per point, grab a CSR slot; write lv into recs[slot] and the slot
// into slotp[point] (unified point index 0..n12).
__global__ void scatter_csr_kernel(const int* __restrict__ c1, int n1,
                                   const int* __restrict__ c2, int n2,
                                   int* __restrict__ cur, int* __restrict__ recs,
                                   int* __restrict__ slotp) {
    int i = blockIdx.x * blockDim.x + threadIdx.x;
    if (i < n1) {
        int4 cc = *reinterpret_cast<const int4*>(c1 + (long long)i * 4);
        int key = voxel_key4(cc);
        int slot = atomicAdd(&cur[key >> 6], 1);
        recs[slot] = key & 63;
        slotp[i] = slot;
    } else if (i < n1 + n2) {
        int j = i - n1;
        int4 cc = *reinterpret_cast<const int4*>(c2 + (long long)j * 4);
        int key = voxel_key4(cc);
        int slot = atomicAdd(&cur[NBIN + (key >> 6)], 1);
        recs[slot] = key & 63;
        slotp[i] = slot;
    }
}

// Copy pass: stream feats SEQUENTIALLY (32 lanes per point, float2/lane),
// pack to bf16x2, nt-store the 128B row to its CSR slot (full-line random
// write; stores don't stall waves).
__global__ __launch_bounds__(256) void copy_kernel(
        const float* __restrict__ f1, const float* __restrict__ f2,
        const int* __restrict__ slotp, unsigned* __restrict__ staging,
        int n1, int n12) {
    int g = (int)(((long long)blockIdx.x * 256 + threadIdx.x) >> 5);  // point
    int lane = threadIdx.x & 31;
    if (g >= n12) return;
    const float* src = (g < n1) ? (f1 + (long long)g * CDIM)
                                : (f2 + (long long)(g - n1) * CDIM);
    f32x2 v = ((const f32x2*)src)[lane];
    unsigned u = (bf16rne(v.y) << 16) | bf16rne(v.x);
    long long slot = slotp[g];
    __builtin_nontemporal_store(u, staging + slot * 32 + lane);
}

// Staged fuse: one block per bin; staging reads are CONTIGUOUS (slots of a
// bin are adjacent). LDS accumulate (atomicMax on ord-encoded, then decode,
// then atomicAdd), contiguous nt writeout.
__global__ __launch_bounds__(256) void fuse_staged_kernel(
        const unsigned* __restrict__ staging, const int* __restrict__ recs,
        const int* __restrict__ pos, const int* __restrict__ cur,
        float* __restrict__ out) {
    __shared__ unsigned acc[BINV * CDIM];   // 16 KB
    __shared__ int rl1[RCAP1];
    __shared__ int rl2[RCAP2];
    int b = blockIdx.x;
    int t = threadIdx.x;
    int b1 = pos[b],        e1 = cur[b];
    int b2 = pos[NBIN + b], e2 = cur[NBIN + b];
    int cnt1 = e1 - b1, cnt2 = e2 - b2;
    int ns1 = min(cnt1, RCAP1), ns2 = min(cnt2, RCAP2);

    #pragma unroll
    for (int k = 0; k < 16; ++k) acc[t + k * 256] = 0u;  // 0 = empty sentinel
    for (int i = t; i < ns2; i += 256) rl2[i] = recs[b2 + i];
    for (int i = t; i < ns1; i += 256) rl1[i] = recs[b1 + i];
    __syncthreads();

    int lane = t & 31;   // channel-pair lane (ch 2*lane, 2*lane+1)
    int grp  = t >> 5;   // 8 point-groups

    // ---- set2: scatter-max into LDS, 8 points/group/iter ----
    for (int base = 0; base < ns2; base += 64) {
        int i0 = base + grp * 8;
        int last = ns2 - 1;
        int lv[8]; unsigned u[8];
        #pragma unroll
        for (int k = 0; k < 8; ++k) lv[k] = rl2[min(i0 + k, last)];
        #pragma unroll
        for (int k = 0; k < 8; ++k)
            u[k] = staging[(long long)(b2 + min(i0 + k, last)) * 32 + lane];
        #pragma unroll
        for (int k = 0; k < 8; ++k) {
            if (i0 + k < ns2) {
                int a = lv[k] * CDIM + 2 * lane;
                atomicMax(&acc[a],     ord_enc(bf16lo(u[k])));
                atomicMax(&acc[a + 1], ord_enc(bf16hi(u[k])));
            }
        }
    }
    // exact tail (bins beyond RCAP2 — statistically never, handled exactly)
    for (int i = ns2 + grp; i < cnt2; i += 8) {
        int lv = recs[b2 + i];
        unsigned u = staging[(long long)(b2 + i) * 32 + lane];
        int a = lv * CDIM + 2 * lane;
        atomicMax(&acc[a],     ord_enc(bf16lo(u)));
        atomicMax(&acc[a + 1], ord_enc(bf16hi(u)));
    }
    __syncthreads();

    // in-place decode: encoded uint -> float bits (0u -> 0.0f)
    #pragma unroll
    for (int k = 0; k < 16; ++k) {
        int w = t + k * 256;
        unsigned u = acc[w];
        acc[w] = __float_as_uint((u == 0u) ? 0.f : ord_dec(u));
    }
    __syncthreads();

    float* facc = (float*)acc;

    // ---- set1: scatter-add onto decoded max, 4 points/group/iter ----
    for (int base = 0; base < ns1; base += 32) {
        int i0 = base + grp * 4;
        int last = ns1 - 1;
        int lv[4]; unsigned u[4];
        #pragma unroll
        for (int k = 0; k < 4; ++k) lv[k] = rl1[min(i0 + k, last)];
        #pragma unroll
        for (int k = 0; k < 4; ++k)
            u[k] = staging[(long long)(b1 + min(i0 + k, last)) * 32 + lane];
        #pragma unroll
        for (int k = 0; k < 4; ++k) {
            if (i0 + k < ns1) {
                int a = lv[k] * CDIM + 2 * lane;
                atomicAdd(&facc[a],     bf16lo(u[k]));
                atomicAdd(&facc[a + 1], bf16hi(u[k]));
            }
        }
    }
    for (int i = ns1 + grp; i < cnt1; i += 8) {
        int lv = recs[b1 + i];
        unsigned u = staging[(long long)(b1 + i) * 32 + lane];
        int a = lv * CDIM + 2 * lane;
        atomicAdd(&facc[a],     bf16lo(u));
        atomicAdd(&facc[a + 1], bf16hi(u));
    }
    __syncthreads();

    // ---- writeout: contiguous 16KB, full-line nt stores ----
    float* ob = out + (long long)b * (BINV * CDIM);
    #pragma unroll
    for (int k = 0; k < 4; ++k) {
        int w = k * 1024 + t * 4;
        f32x4 val = *(f32x4*)&facc[w];
        __builtin_nontemporal_store(val, (f32x4*)(ob + w));
    }
}

// ================= TIER 2: round-8 fixed-capacity path (exact f32) =========

__global__ void scatter_fixed_kernel(const int* __restrict__ c1, int n1,
                                     const int* __restrict__ c2, int n2,
                                     int* __restrict__ cnt, int* __restrict__ dirty,
                                     int* __restrict__ ctr, int* __restrict__ dlist,
                                     int* __restrict__ ovf, int* __restrict__ recs) {
    int i = blockIdx.x * blockDim.x + threadIdx.x;
    int rec = 0, cslot = 0, bin = 0, capv = 0, rbase = 0;
    bool valid = false;
    if (i < n1) {
        int4 cc = *reinterpret_cast<const int4*>(c1 + (long long)i * 4);
        int key = voxel_key4(cc);
        bin = key >> 6; rec = (i << 6) | (key & 63);
        cslot = 2 * bin;     capv = CAP1; rbase = bin * CAPT;        valid = true;
    } else if (i < n1 + n2) {
        int j = i - n1;
        int4 cc = *reinterpret_cast<const int4*>(c2 + (long long)j * 4);
        int key = voxel_key4(cc);
        bin = key >> 6; rec = (j << 6) | (key & 63);
        cslot = 2 * bin + 1; capv = CAP2; rbase = bin * CAPT + CAP1; valid = true;
    }
    if (valid) {
        int c = atomicAdd(&cnt[cslot], 1);
        if (c < capv) {
            recs[rbase + c] = rec;
        } else {
            int o = atomicAdd(&ctr[1], 1);
            if (o < OVFCAP) { ovf[2 * o] = rec; ovf[2 * o + 1] = cslot; }
            if (atomicExch(&dirty[bin], 1) == 0) {
                int d = atomicAdd(&ctr[0], 1);
                dlist[d] = bin;
            }
        }
    }
}

__global__ __launch_bounds__(256) void fuse_fixed_kernel(
        const float* __restrict__ f1, const float* __restrict__ f2,
        const int* __restrict__ recs, const int* __restrict__ cnt,
        float* __restrict__ out) {
    __shared__ unsigned acc[BINV * CDIM];
    __shared__ int rl1[CAP1];
    __shared__ int rl2[CAP2];
    int b = blockIdx.x;
    int t = threadIdx.x;
    int c1 = cnt[2 * b], c2 = cnt[2 * b + 1];
    int ns1 = min(c1, CAP1), ns2 = min(c2, CAP2);
    const int rb = b * CAPT;
    #pragma unroll
    for (int k = 0; k < 16; ++k) acc[t + k * 256] = 0u;
    for (int i = t; i < ns2; i += 256) rl2[i] = recs[rb + CAP1 + i];
    for (int i = t; i < ns1; i += 256) rl1[i] = recs[rb + i];
    __syncthreads();
    int lane = t & 31, grp = t >> 5;
    for (int base = 0; base < ns2; base += 64) {
        int i0 = base + grp * 8, last = ns2 - 1;
        int rr[8]; f32x2 d[8];
        #pragma unroll
        for (int k = 0; k < 8; ++k) rr[k] = rl2[min(i0 + k, last)];
        #pragma unroll
        for (int k = 0; k < 8; ++k)
            d[k] = ((const f32x2*)(f2 + (long long)(rr[k] >> 6) * CDIM))[lane];
        #pragma unroll
        for (int k = 0; k < 8; ++k) {
            if (i0 + k < ns2) {
                int a = (rr[k] & 63) * CDIM + 2 * lane;
                atomicMax(&acc[a],     ord_enc(d[k].x));
                atomicMax(&acc[a + 1], ord_enc(d[k].y));
            }
        }
    }
    __syncthreads();
    #pragma unroll
    for (int k = 0; k < 16; ++k) {
        int w = t + k * 256;
        unsigned u = acc[w];
        acc[w] = __float_as_uint((u == 0u) ? 0.f : ord_dec(u));
    }
    __syncthreads();
    float* facc = (float*)acc;
    for (int base = 0; base < ns1; base += 32) {
        int i0 = base + grp * 4, last = ns1 - 1;
        int rr[4]; f32x2 d[4];
        #pragma unroll
        for (int k = 0; k < 4; ++k) rr[k] = rl1[min(i0 + k, last)];
        #pragma unroll
        for (int k = 0; k < 4; ++k)
            d[k] = ((const f32x2*)(f1 + (long long)(rr[k] >> 6) * CDIM))[lane];
        #pragma unroll
        for (int k = 0; k < 4; ++k) {
            if (i0 + k < ns1) {
                int a = (rr[k] & 63) * CDIM + 2 * lane;
                atomicAdd(&facc[a],     d[k].x);
                atomicAdd(&facc[a + 1], d[k].y);
            }
        }
    }
    __syncthreads();
    float* ob = out + (long long)b * (BINV * CDIM);
    #pragma unroll
    for (int k = 0; k < 4; ++k) {
        int w = k * 1024 + t * 4;
        f32x4 val = *(f32x4*)&facc[w];
        __builtin_nontemporal_store(val, (f32x4*)(ob + w));
    }
}

__global__ __launch_bounds__(256) void fixup_kernel(
        const float* __restrict__ f1, const float* __restrict__ f2,
        const int* __restrict__ recs, const int* __restrict__ cnt,
        const int* __restrict__ ctr, const int* __restrict__ dlist,
        const int* __restrict__ ovf, float* __restrict__ out) {
    __shared__ unsigned acc[BINV * CDIM];
    int nd = ctr[0];
    int novf = min(ctr[1], OVFCAP);
    int t = threadIdx.x;
    int lane = t & 31, grp = t >> 5;
    for (int d = blockIdx.x; d < nd; d += gridDim.x) {
        int b = dlist[d];
        int c1 = cnt[2 * b], c2 = cnt[2 * b + 1];
        int ns1 = min(c1, CAP1), ns2 = min(c2, CAP2);
        #pragma unroll
        for (int k = 0; k < 16; ++k) acc[t + k * 256] = 0u;
        __syncthreads();
        for (int i = grp; i < ns2; i += 8) {
            int rec = recs[b * CAPT + CAP1 + i];
            const float* p = f2 + (long long)(rec >> 6) * CDIM;
            int lv = (rec & 63) * CDIM;
            atomicMax(&acc[lv + lane],      ord_enc(p[lane]));
            atomicMax(&acc[lv + lane + 32], ord_enc(p[lane + 32]));
        }
        for (int i = grp; i < novf; i += 8) {
            if (ovf[2 * i + 1] == 2 * b + 1) {
                int rec = ovf[2 * i];
                const float* p = f2 + (long long)(rec >> 6) * CDIM;
                int lv = (rec & 63) * CDIM;
                atomicMax(&acc[lv + lane],      ord_enc(p[lane]));
                atomicMax(&acc[lv + lane + 32], ord_enc(p[lane + 32]));
            }
        }
        __syncthreads();
        #pragma unroll
        for (int k = 0; k < 16; ++k) {
            int w = t + k * 256;
            unsigned u = acc[w];
            acc[w] = __float_as_uint((u == 0u) ? 0.f : ord_dec(u));
        }
        __syncthreads();
        float* facc = (float*)acc;
        for (int i = grp; i < ns1; i += 8) {
            int rec = recs[b * CAPT + i];
            const float* p = f1 + (long long)(rec >> 6) * CDIM;
            int lv = (rec & 63) * CDIM;
            atomicAdd(&facc[lv + lane],      p[lane]);
            atomicAdd(&facc[lv + lane + 32], p[lane + 32]);
        }
        for (int i = grp; i < novf; i += 8) {
            if (ovf[2 * i + 1] == 2 * b) {
                int rec = ovf[2 * i];
                const float* p = f1 + (long long)(rec >> 6) * CDIM;
                int lv = (rec & 63) * CDIM;
                atomicAdd(&facc[lv + lane],      p[lane]);
                atomicAdd(&facc[lv + lane + 32], p[lane + 32]);
            }
        }
        __syncthreads();
        float* ob = out + (long long)b * (BINV * CDIM);
        #pragma unroll
        for (int k = 0; k < 4; ++k) {
            int w = k * 1024 + t * 4;
            *(f32x4*)(ob + w) = *(f32x4*)&facc[w];
        }
        __syncthreads();
    }
}

// ================= TIER 3: atomic fallback ==================================

__global__ void fb_scatter_max(const float* __restrict__ feats, const int* __restrict__ coords,
                               unsigned* __restrict__ out, int npts) {
    long long i = (long long)blockIdx.x * blockDim.x + threadIdx.x;
    if (i >= (long long)npts * (CDIM / 4)) return;
    int pt = (int)(i >> 4), c4 = (int)(i & 15);
    int4 cc = *reinterpret_cast<const int4*>(coords + (long long)pt * 4);
    int key = voxel_key4(cc);
    float4 f = *reinterpret_cast<const float4*>(feats + (long long)pt * CDIM + c4 * 4);
    unsigned* dst = out + (long long)key * CDIM + c4 * 4;
    atomicMax(dst + 0, ord_enc(f.x));
    atomicMax(dst + 1, ord_enc(f.y));
    atomicMax(dst + 2, ord_enc(f.z));
    atomicMax(dst + 3, ord_enc(f.w));
}
__global__ void fb_decode(unsigned* __restrict__ buf, long long n4) {
    long long i = (long long)blockIdx.x * blockDim.x + threadIdx.x;
    if (i >= n4) return;
    uint4 u = reinterpret_cast<const uint4*>(buf)[i];
    float4 f;
    f.x = (u.x == 0u) ? 0.f : ord_dec(u.x);
    f.y = (u.y == 0u) ? 0.f : ord_dec(u.y);
    f.z = (u.z == 0u) ? 0.f : ord_dec(u.z);
    f.w = (u.w == 0u) ? 0.f : ord_dec(u.w);
    reinterpret_cast<float4*>(buf)[i] = f;
}
__global__ void fb_scatter_add(const float* __restrict__ feats, const int* __restrict__ coords,
                               float* __restrict__ out, int npts) {
    long long i = (long long)blockIdx.x * blockDim.x + threadIdx.x;
    if (i >= (long long)npts * (CDIM / 4)) return;
    int pt = (int)(i >> 4), c4 = (int)(i & 15);
    int4 cc = *reinterpret_cast<const int4*>(coords + (long long)pt * 4);
    int key = voxel_key4(cc);
    float4 f = *reinterpret_cast<const float4*>(feats + (long long)pt * CDIM + c4 * 4);
    float* dst = out + (long long)key * CDIM + c4 * 4;
    atomicAdd(dst + 0, f.x); atomicAdd(dst + 1, f.y);
    atomicAdd(dst + 2, f.z); atomicAdd(dst + 3, f.w);
}

extern "C" void kernel_launch(void* const* d_in, const int* in_sizes, int n_in,
                              void* d_out, int out_size, void* d_ws, size_t ws_size,
                              hipStream_t stream) {
    const float* feats1 = (const float*)d_in[0];
    const int*   coords1 = (const int*)d_in[1];
    const float* feats2 = (const float*)d_in[2];
    const int*   coords2 = (const int*)d_in[3];
    float* out = (float*)d_out;

    const int n1 = in_sizes[1] / 4;
    const int n2 = in_sizes[3] / 4;
    const int n12 = n1 + n2;
    const long long kc = (long long)KSLOTS * CDIM;
    const int nb12 = (n12 + 255) / 256;

    // ---- tier 1: exact CSR + bf16 staging ----
    // ints: cnt/cur[NBIN2] | pos[NBIN2] | recs[n12] | slotp[n12] | staging[32*n12]
    const size_t need1 = ((size_t)2 * NBIN2 + 2 * (size_t)n12 + 32 * (size_t)n12)
                         * sizeof(int);
    if (ws_size >= need1) {
        int* cnt  = (int*)d_ws;               // hist -> cursor -> ends
        int* pos  = cnt + NBIN2;              // starts
        int* recs = pos + NBIN2;              // lv per slot
        int* slotp = recs + n12;              // slot per point
        unsigned* staging = (unsigned*)(slotp + n12);

        hipMemsetAsync(cnt, 0, (size_t)NBIN2 * sizeof(int), stream);
        hist2_kernel<<<nb12, 256, 0, stream>>>(coords1, n1, coords2, n2, cnt);
        scan_kernel<<<1, SCAN_T, 0, stream>>>(cnt, pos);
        scatter_csr_kernel<<<nb12, 256, 0, stream>>>(coords1, n1, coords2, n2,
                                                     cnt, recs, slotp);
        int cpblocks = (int)(((long long)n12 * 32 + 255) / 256);
        copy_kernel<<<cpblocks, 256, 0, stream>>>(feats1, feats2, slotp, staging,
                                                  n1, n12);
        fuse_staged_kernel<<<NBIN, 256, 0, stream>>>(staging, recs, pos, cnt, out);
        return;
    }

    // ---- tier 2: round-8 fixed-capacity path ----
    const size_t need2 = ((size_t)3 * NBIN + 2 + NBIN + 2 * OVFCAP
                          + (size_t)NBIN * CAPT) * sizeof(int);
    if (ws_size >= need2) {
        int* cnt   = (int*)d_ws;
        int* dirty = cnt + 2 * NBIN;
        int* ctr   = dirty + NBIN;
        int* dlist = ctr + 2;
        int* ovf   = dlist + NBIN;
        int* recs  = ovf + 2 * OVFCAP;
        hipMemsetAsync(cnt, 0, ((size_t)3 * NBIN + 2) * sizeof(int), stream);
        scatter_fixed_kernel<<<nb12, 256, 0, stream>>>(coords1, n1, coords2, n2,
                                                       cnt, dirty, ctr, dlist, ovf, recs);
        fuse_fixed_kernel<<<NBIN, 256, 0, stream>>>(feats1, feats2, recs, cnt, out);
        fixup_kernel<<<64, 256, 0, stream>>>(feats1, feats2, recs, cnt, ctr, dlist,
                                             ovf, out);
        return;
    }

    // ---- tier 3: atomic fallback ----
    hipMemsetAsync(d_out, 0, kc * sizeof(float), stream);
    long long t2 = (long long)n2 * (CDIM / 4);
    fb_scatter_max<<<(int)((t2 + 255) / 256), 256, 0, stream>>>(feats2, coords2,
                                                                (unsigned*)out, n2);
    long long q = kc / 4;
    fb_decode<<<(int)((q + 255) / 256), 256, 0, stream>>>((unsigned*)out, q);
    long long t1 = (long long)n1 * (CDIM / 4);
    fb_scatter_add<<<(int)((t1 + 255) / 256), 256, 0, stream>>>(feats1, coords1, out, n1);
}

// Round 11
// 185.232 us; speedup vs baseline: 1.8107x; 1.8107x over previous
//
#include <hip/hip_runtime.h>
#include <float.h>

// Grid dims from the reference
#define BDIM 4
#define ZDIM 6
#define YDIM 200
#define XDIM 176
#define CDIM 64
#define KSLOTS (BDIM * ZDIM * YDIM * XDIM)  // 844800
#define BINV 64                              // voxels per bin
#define NBIN (KSLOTS / BINV)                 // 13200
#define CAP1 64                              // fixed slots/bin, set1 (mean ~15)
#define CAP2 192                             // fixed slots/bin, set2 (mean ~61)
#define CAPT (CAP1 + CAP2)                   // 256 recs per bin
#define OVFCAP 16384

typedef float f32x4 __attribute__((ext_vector_type(4)));
typedef float f32x2 __attribute__((ext_vector_type(2)));

__device__ __forceinline__ int voxel_key4(const int4 c) {
    return ((c.x * ZDIM + c.y) * YDIM + c.z) * XDIM + c.w;
}
// monotonic float<->uint order encoding; 0u = "empty" sentinel (below all reals)
__device__ __forceinline__ unsigned ord_enc(float f) {
    unsigned u = __float_as_uint(f);
    return (u & 0x80000000u) ? ~u : (u | 0x80000000u);
}
__device__ __forceinline__ float ord_dec(unsigned u) {
    return (u & 0x80000000u) ? __uint_as_float(u & 0x7FFFFFFFu)
                             : __uint_as_float(~u);
}

// ---------------- single-pass fixed-capacity scatter ----------------
// recs[bin*CAPT + 0..CAP1)    = set1 records (point<<6 | local_voxel)
// recs[bin*CAPT + CAP1..CAPT) = set2 records
// Overflow (statistically never): record -> ovf list, bin -> dirty flag;
// fuse_kernel handles dirty bins exactly via the ovf list.
__global__ void scatter_fixed_kernel(const int* __restrict__ c1, int n1,
                                     const int* __restrict__ c2, int n2,
                                     int* __restrict__ cnt, int* __restrict__ dirty,
                                     int* __restrict__ ctr,
                                     int* __restrict__ ovf, int* __restrict__ recs) {
    int i = blockIdx.x * blockDim.x + threadIdx.x;
    int rec = 0, cslot = 0, bin = 0, capv = 0, rbase = 0;
    bool valid = false;
    if (i < n1) {
        int4 cc = *reinterpret_cast<const int4*>(c1 + (long long)i * 4);
        int key = voxel_key4(cc);
        bin = key >> 6; rec = (i << 6) | (key & 63);
        cslot = 2 * bin;     capv = CAP1; rbase = bin * CAPT;        valid = true;
    } else if (i < n1 + n2) {
        int j = i - n1;
        int4 cc = *reinterpret_cast<const int4*>(c2 + (long long)j * 4);
        int key = voxel_key4(cc);
        bin = key >> 6; rec = (j << 6) | (key & 63);
        cslot = 2 * bin + 1; capv = CAP2; rbase = bin * CAPT + CAP1; valid = true;
    }
    if (valid) {
        int c = atomicAdd(&cnt[cslot], 1);
        if (c < capv) {
            recs[rbase + c] = rec;
        } else {
            int o = atomicAdd(&ctr[1], 1);
            if (o < OVFCAP) { ovf[2 * o] = rec; ovf[2 * o + 1] = cslot; }
            dirty[bin] = 1;
        }
    }
}

// ---------------- fused bin-local accumulate (fixup folded in) ----------
// One block per bin (64 voxels x 64 ch = 16KB LDS tile). float2 row reads:
// one vmem instruction per point (lane reads ch 2*lane, 2*lane+1).
// LDS atomics land 2 lanes/bank (free). Dirty bins additionally scan the
// global overflow list (statistically never taken).
__global__ __launch_bounds__(256) void fuse_kernel(
        const float* __restrict__ f1, const float* __restrict__ f2,
        const int* __restrict__ recs, const int* __restrict__ cnt,
        const int* __restrict__ dirty, const int* __restrict__ ctr,
        const int* __restrict__ ovf, float* __restrict__ out) {
    __shared__ unsigned acc[BINV * CDIM];   // 16 KB (encoded uints, then floats)
    __shared__ int rl1[CAP1];
    __shared__ int rl2[CAP2];
    int b = blockIdx.x;
    int t = threadIdx.x;
    int c1 = cnt[2 * b], c2 = cnt[2 * b + 1];
    int ns1 = min(c1, CAP1), ns2 = min(c2, CAP2);
    int isdirty = dirty[b];
    const int rb = b * CAPT;

    #pragma unroll
    for (int k = 0; k < 16; ++k) acc[t + k * 256] = 0u;  // 0 = empty sentinel
    for (int i = t; i < ns2; i += 256) rl2[i] = recs[rb + CAP1 + i];
    for (int i = t; i < ns1; i += 256) rl1[i] = recs[rb + i];
    __syncthreads();

    int lane = t & 31;   // channel-pair lane (ch 2*lane, 2*lane+1)
    int grp  = t >> 5;   // 8 point-groups

    // ---- set2: scatter-max into LDS, 8 points/group/iter ----
    for (int base = 0; base < ns2; base += 64) {
        int i0 = base + grp * 8;
        int last = ns2 - 1;
        int rr[8]; f32x2 d[8];
        #pragma unroll
        for (int k = 0; k < 8; ++k) rr[k] = rl2[min(i0 + k, last)];
        #pragma unroll
        for (int k = 0; k < 8; ++k)
            d[k] = ((const f32x2*)(f2 + (long long)(rr[k] >> 6) * CDIM))[lane];
        #pragma unroll
        for (int k = 0; k < 8; ++k) {
            if (i0 + k < ns2) {
                int a = (rr[k] & 63) * CDIM + 2 * lane;
                atomicMax(&acc[a],     ord_enc(d[k].x));
                atomicMax(&acc[a + 1], ord_enc(d[k].y));
            }
        }
    }
    // overflow records for this bin (statistically never)
    if (isdirty) {
        int novf = min(ctr[1], OVFCAP);
        for (int i = grp; i < novf; i += 8) {
            if (ovf[2 * i + 1] == 2 * b + 1) {
                int rec = ovf[2 * i];
                f32x2 d = ((const f32x2*)(f2 + (long long)(rec >> 6) * CDIM))[lane];
                int a = (rec & 63) * CDIM + 2 * lane;
                atomicMax(&acc[a],     ord_enc(d.x));
                atomicMax(&acc[a + 1], ord_enc(d.y));
            }
        }
    }
    __syncthreads();

    // in-place decode: encoded uint -> float bits (0u -> 0.0f)
    #pragma unroll
    for (int k = 0; k < 16; ++k) {
        int w = t + k * 256;
        unsigned u = acc[w];
        acc[w] = __float_as_uint((u == 0u) ? 0.f : ord_dec(u));
    }
    __syncthreads();

    float* facc = (float*)acc;

    // ---- set1: scatter-add onto decoded max, 4 points/group/iter ----
    for (int base = 0; base < ns1; base += 32) {
        int i0 = base + grp * 4;
        int last = ns1 - 1;
        int rr[4]; f32x2 d[4];
        #pragma unroll
        for (int k = 0; k < 4; ++k) rr[k] = rl1[min(i0 + k, last)];
        #pragma unroll
        for (int k = 0; k < 4; ++k)
            d[k] = ((const f32x2*)(f1 + (long long)(rr[k] >> 6) * CDIM))[lane];
        #pragma unroll
        for (int k = 0; k < 4; ++k) {
            if (i0 + k < ns1) {
                int a = (rr[k] & 63) * CDIM + 2 * lane;
                atomicAdd(&facc[a],     d[k].x);
                atomicAdd(&facc[a + 1], d[k].y);
            }
        }
    }
    if (isdirty) {
        int novf = min(ctr[1], OVFCAP);
        for (int i = grp; i < novf; i += 8) {
            if (ovf[2 * i + 1] == 2 * b) {
                int rec = ovf[2 * i];
                f32x2 d = ((const f32x2*)(f1 + (long long)(rec >> 6) * CDIM))[lane];
                int a = (rec & 63) * CDIM + 2 * lane;
                atomicAdd(&facc[a],     d.x);
                atomicAdd(&facc[a + 1], d.y);
            }
        }
    }
    __syncthreads();

    // ---- writeout: contiguous 16KB, full-line nt stores ----
    float* ob = out + (long long)b * (BINV * CDIM);
    #pragma unroll
    for (int k = 0; k < 4; ++k) {
        int w = k * 1024 + t * 4;
        f32x4 val = *(f32x4*)&facc[w];
        __builtin_nontemporal_store(val, (f32x4*)(ob + w));
    }
}

// ---------------- fallback (atomic path, used only if ws too small) ----------

__global__ void fb_scatter_max(const float* __restrict__ feats, const int* __restrict__ coords,
                               unsigned* __restrict__ out, int npts) {
    long long i = (long long)blockIdx.x * blockDim.x + threadIdx.x;
    if (i >= (long long)npts * (CDIM / 4)) return;
    int pt = (int)(i >> 4), c4 = (int)(i & 15);
    int4 cc = *reinterpret_cast<const int4*>(coords + (long long)pt * 4);
    int key = voxel_key4(cc);
    float4 f = *reinterpret_cast<const float4*>(feats + (long long)pt * CDIM + c4 * 4);
    unsigned* dst = out + (long long)key * CDIM + c4 * 4;
    atomicMax(dst + 0, ord_enc(f.x));
    atomicMax(dst + 1, ord_enc(f.y));
    atomicMax(dst + 2, ord_enc(f.z));
    atomicMax(dst + 3, ord_enc(f.w));
}
__global__ void fb_decode(unsigned* __restrict__ buf, long long n4) {
    long long i = (long long)blockIdx.x * blockDim.x + threadIdx.x;
    if (i >= n4) return;
    uint4 u = reinterpret_cast<const uint4*>(buf)[i];
    float4 f;
    f.x = (u.x == 0u) ? 0.f : ord_dec(u.x);
    f.y = (u.y == 0u) ? 0.f : ord_dec(u.y);
    f.z = (u.z == 0u) ? 0.f : ord_dec(u.z);
    f.w = (u.w == 0u) ? 0.f : ord_dec(u.w);
    reinterpret_cast<float4*>(buf)[i] = f;
}
__global__ void fb_scatter_add(const float* __restrict__ feats, const int* __restrict__ coords,
                               float* __restrict__ out, int npts) {
    long long i = (long long)blockIdx.x * blockDim.x + threadIdx.x;
    if (i >= (long long)npts * (CDIM / 4)) return;
    int pt = (int)(i >> 4), c4 = (int)(i & 15);
    int4 cc = *reinterpret_cast<const int4*>(coords + (long long)pt * 4);
    int key = voxel_key4(cc);
    float4 f = *reinterpret_cast<const float4*>(feats + (long long)pt * CDIM + c4 * 4);
    float* dst = out + (long long)key * CDIM + c4 * 4;
    atomicAdd(dst + 0, f.x); atomicAdd(dst + 1, f.y);
    atomicAdd(dst + 2, f.z); atomicAdd(dst + 3, f.w);
}

extern "C" void kernel_launch(void* const* d_in, const int* in_sizes, int n_in,
                              void* d_out, int out_size, void* d_ws, size_t ws_size,
                              hipStream_t stream) {
    const float* feats1 = (const float*)d_in[0];
    const int*   coords1 = (const int*)d_in[1];
    const float* feats2 = (const float*)d_in[2];
    const int*   coords2 = (const int*)d_in[3];
    float* out = (float*)d_out;

    const int n1 = in_sizes[1] / 4;
    const int n2 = in_sizes[3] / 4;
    const int n12 = n1 + n2;
    const long long kc = (long long)KSLOTS * CDIM;

    // ws layout (ints): cnt[2*NBIN] | dirty[NBIN] | ctr[2] |
    //                   ovf[2*OVFCAP] | recs[NBIN*CAPT]
    const size_t needed = ((size_t)3 * NBIN + 2 + 2 * OVFCAP
                           + (size_t)NBIN * CAPT) * sizeof(int);
    if (ws_size < needed) {
        hipMemsetAsync(d_out, 0, kc * sizeof(float), stream);
        long long t2 = (long long)n2 * (CDIM / 4);
        fb_scatter_max<<<(int)((t2 + 255) / 256), 256, 0, stream>>>(feats2, coords2,
                                                                    (unsigned*)out, n2);
        long long q = kc / 4;
        fb_decode<<<(int)((q + 255) / 256), 256, 0, stream>>>((unsigned*)out, q);
        long long t1 = (long long)n1 * (CDIM / 4);
        fb_scatter_add<<<(int)((t1 + 255) / 256), 256, 0, stream>>>(feats1, coords1, out, n1);
        return;
    }

    int* cnt   = (int*)d_ws;
    int* dirty = cnt + 2 * NBIN;
    int* ctr   = dirty + NBIN;
    int* ovf   = ctr + 2;
    int* recs  = ovf + 2 * OVFCAP;

    // zero cnt + dirty + ctr (contiguous prefix, 158 KB)
    hipMemsetAsync(cnt, 0, ((size_t)3 * NBIN + 2) * sizeof(int), stream);

    int nb12 = (n12 + 255) / 256;
    scatter_fixed_kernel<<<nb12, 256, 0, stream>>>(coords1, n1, coords2, n2,
                                                   cnt, dirty, ctr, ovf, recs);
    fuse_kernel<<<NBIN, 256, 0, stream>>>(feats1, feats2, recs, cnt, dirty, ctr,
                                          ovf, out);
}